// Round 10
// baseline (116.642 us; speedup 1.0000x reference)
//
#include <hip/hip_runtime.h>
#include <cstdint>
#include <cstddef>

#define LOG2E 1.44269504088896340736f

typedef float  f32x16 __attribute__((ext_vector_type(16)));
typedef __bf16 bf16x8 __attribute__((ext_vector_type(8)));

union BF8 { bf16x8 v; uint u[4]; ushort us[8]; };

// pack two floats to bf16 pair (round-half-up), a -> lo16, b -> hi16
__device__ __forceinline__ uint pack_bf(float a, float b) {
    uint ua = __float_as_uint(a) + 0x8000u;
    uint ub = __float_as_uint(b) + 0x8000u;
    return __builtin_amdgcn_perm(ub, ua, 0x07060302u);
}
// pack two floats to bf16 pair via HW cvt (RNE), a -> lo16, b -> hi16
__device__ __forceinline__ uint cvt_pk_bf(float a, float b) {
    uint r;
    asm("v_cvt_pk_bf16_f32 %0, %1, %2" : "=v"(r) : "v"(a), "v"(b));
    return r;
}

// ---------------------------------------------------------------------------
// lnqkv: FUSED LayerNorm + QKV/conv MFMA GEMMs. One block = one 32-px group,
// 1024 threads / 16 waves. Weight A-fragments are loaded as FP32 at kernel
// entry and packed to bf16 ONCE (outside all hot loops; Q-scale folded into
// the fp32 mul before pack_bf -> bit-identical to the old convert_w path).
// Their load latency hides under the LN phase (T14). No convert kernel.
// grid 256 x 1024.
// ---------------------------------------------------------------------------
__global__ __launch_bounds__(1024) void lnqkv_kernel(
    const float* __restrict__ x, const float* __restrict__ nw, const float* __restrict__ nb,
    const float* __restrict__ qkv_w, const float* __restrict__ c1w,
    const float* __restrict__ c1b, const float* __restrict__ c2w,
    const float* __restrict__ c2b,
    ushort* __restrict__ Qb, ushort* __restrict__ Kb, ushort* __restrict__ Vsw,
    float* __restrict__ dynb)
{
    __shared__ union {
        struct {
            uint  XN[32 * 32 * 4];   // [u][px][4 uint=8 bf16] 16 KB
            uint  XR[32 * 32 * 4];   // raw x, same layout     16 KB
            float red1[1024];        //                         4 KB
            float red2[1024];        //                         4 KB
        } p;
        float trans[10][33 * 32];    // epilogue, aliases above (42.2 KB)
    } S;
    __shared__ float muS[32], rsS[32];
    __shared__ float dpart[4][32];

    const int t    = threadIdx.x;
    const int pg   = blockIdx.x;
    const int b    = pg >> 7;
    const int n0   = (pg & 127) * 32;
    const int w    = t >> 6;          // 0..15
    const int lane = t & 63;
    const int m    = lane & 31;       // A-row / C-col index (= px for B)
    const int h    = lane >> 5;       // k-slot half

    // ---- A-fragment preload: fp32 load + one-time pack (entry, not in loop) ----
    bf16x8 afr[16];
    if (w < 10) {
        const float sc = (w < 2) ? 0.25f * LOG2E : 1.f;   // Q tiles pre-scaled
        const float* ap;
        if (w < 6) {
            const int qkv = w >> 1;   // 0=Q 1=K 2=V
            const int ti  = w & 1;
            ap = qkv_w + (size_t)(qkv * 64 + ti * 32 + m) * 256 + h * 8;
        } else {
            ap = c1w + (size_t)((w - 6) * 32 + m) * 256 + h * 8;
        }
        #pragma unroll
        for (int ks = 0; ks < 16; ++ks) {
            float4 a0 = *(const float4*)(ap + ks * 16);
            float4 a1 = *(const float4*)(ap + ks * 16 + 4);
            BF8 af;
            af.u[0] = pack_bf(a0.x * sc, a0.y * sc);
            af.u[1] = pack_bf(a0.z * sc, a0.w * sc);
            af.u[2] = pack_bf(a1.x * sc, a1.y * sc);
            af.u[3] = pack_bf(a1.z * sc, a1.w * sc);
            afr[ks] = af.v;
        }
    }

    // ------------------ Phase 1: LayerNorm into LDS ------------------
    {
        const int j  = t & 31;            // px
        const int cg = t >> 5;            // channel group (8 ch each), 0..31
        const size_t xb = (size_t)b * 256 * 4096 + n0 + j;
        float v[8];
        #pragma unroll
        for (int i = 0; i < 8; ++i) v[i] = x[xb + (size_t)(cg * 8 + i) * 4096];
        float s1 = 0.f, s2 = 0.f;
        #pragma unroll
        for (int i = 0; i < 8; ++i) { s1 += v[i]; s2 += v[i] * v[i]; }
        uint4 pk;
        pk.x = pack_bf(v[0], v[1]); pk.y = pack_bf(v[2], v[3]);
        pk.z = pack_bf(v[4], v[5]); pk.w = pack_bf(v[6], v[7]);
        *(uint4*)&S.p.XR[(cg * 32 + j) * 4] = pk;
        S.p.red1[t] = s1; S.p.red2[t] = s2;
        __syncthreads();
        if (t < 32) {
            float a = 0.f, q = 0.f;
            #pragma unroll 8
            for (int g2 = 0; g2 < 32; ++g2) { a += S.p.red1[g2 * 32 + t]; q += S.p.red2[g2 * 32 + t]; }
            float mu  = a * (1.f / 256.f);
            float var = q * (1.f / 256.f) - mu * mu;
            muS[t] = mu; rsS[t] = rsqrtf(fmaxf(var, 0.f) + 1e-5f);
        }
        __syncthreads();
        const float mu = muS[j], rs = rsS[j];
        const float4 w0 = *(const float4*)(nw + cg * 8);
        const float4 w1 = *(const float4*)(nw + cg * 8 + 4);
        const float4 b0 = *(const float4*)(nb + cg * 8);
        const float4 b1 = *(const float4*)(nb + cg * 8 + 4);
        float e0 = (v[0] - mu) * rs * w0.x + b0.x;
        float e1 = (v[1] - mu) * rs * w0.y + b0.y;
        float e2 = (v[2] - mu) * rs * w0.z + b0.z;
        float e3 = (v[3] - mu) * rs * w0.w + b0.w;
        float e4 = (v[4] - mu) * rs * w1.x + b1.x;
        float e5 = (v[5] - mu) * rs * w1.y + b1.y;
        float e6 = (v[6] - mu) * rs * w1.z + b1.z;
        float e7 = (v[7] - mu) * rs * w1.w + b1.w;
        uint4 o;
        o.x = pack_bf(e0, e1); o.y = pack_bf(e2, e3);
        o.z = pack_bf(e4, e5); o.w = pack_bf(e6, e7);
        *(uint4*)&S.p.XN[(cg * 32 + j) * 4] = o;
    }
    __syncthreads();

    // ------------------ Phase 2: MFMA GEMMs from LDS + reg A ------------------
    const ushort* xnB = (const ushort*)S.p.XN;
    const ushort* xrB = (const ushort*)S.p.XR;

    f32x16 acc;
    #pragma unroll
    for (int i = 0; i < 16; ++i) acc[i] = 0.f;

    if (w < 6) {
        #pragma unroll
        for (int ks = 0; ks < 16; ++ks) {
            bf16x8 bf = *(const bf16x8*)(xnB + ((ks * 2 + h) * 32 + m) * 8);
            acc = __builtin_amdgcn_mfma_f32_32x32x16_bf16(afr[ks], bf, acc, 0, 0, 0);
        }
    } else if (w < 10) {
        #pragma unroll
        for (int ks = 0; ks < 16; ++ks) {
            bf16x8 bf = *(const bf16x8*)(xrB + ((ks * 2 + h) * 32 + m) * 8);
            acc = __builtin_amdgcn_mfma_f32_32x32x16_bf16(afr[ks], bf, acc, 0, 0, 0);
        }
    }
    __syncthreads();   // all XN/XR reads done; trans (aliased) now writable

    if (w < 10) {
        float* tr = S.trans[w];
        #pragma unroll
        for (int r = 0; r < 16; ++r)
            tr[((r & 3) + 8 * (r >> 2) + 4 * h) * 33 + m] = acc[r];

        if (w < 4) {                       // Q/K tiles
            const int qkv = w >> 1, ti = w & 1;
            ushort* dst = (qkv == 0) ? Qb : Kb;
            #pragma unroll
            for (int it = 0; it < 2; ++it) {
                int unit = it * 2 + h;            // 0..3
                int hl = unit >> 1, half = unit & 1;
                float v0 = tr[(hl * 16 + half * 8 + 0) * 33 + m];
                float v1 = tr[(hl * 16 + half * 8 + 1) * 33 + m];
                float v2 = tr[(hl * 16 + half * 8 + 2) * 33 + m];
                float v3 = tr[(hl * 16 + half * 8 + 3) * 33 + m];
                float v4 = tr[(hl * 16 + half * 8 + 4) * 33 + m];
                float v5 = tr[(hl * 16 + half * 8 + 5) * 33 + m];
                float v6 = tr[(hl * 16 + half * 8 + 6) * 33 + m];
                float v7 = tr[(hl * 16 + half * 8 + 7) * 33 + m];
                uint4 pk;
                pk.x = pack_bf(v0, v1); pk.y = pack_bf(v2, v3);
                pk.z = pack_bf(v4, v5); pk.w = pack_bf(v6, v7);
                int head = ti * 2 + hl;
                *(uint4*)(dst + ((size_t)(b * 4 + head) * 4096 + n0 + m) * 16 + half * 8) = pk;
            }
        } else if (w < 6) {                // V tile
            const int ti = w & 1;
            int d = lane & 15, u = lane >> 4;
            #pragma unroll
            for (int it = 0; it < 4; ++it) {
                int unit = it * 4 + u;            // 0..15
                int hl = unit >> 3, sg = unit & 7;
                float v0 = tr[(hl * 16 + d) * 33 + sg * 4 + 0];
                float v1 = tr[(hl * 16 + d) * 33 + sg * 4 + 1];
                float v2 = tr[(hl * 16 + d) * 33 + sg * 4 + 2];
                float v3 = tr[(hl * 16 + d) * 33 + sg * 4 + 3];
                uint2 pk; pk.x = pack_bf(v0, v1); pk.y = pack_bf(v2, v3);
                int head = ti * 2 + hl;
                *(uint2*)(Vsw + (((size_t)(b * 4 + head) * 1024 + (pg & 127) * 8 + sg) * 16 + d) * 4) = pk;
            }
        } else {                           // conv tile ti = w-6
            const int ti = w - 6;
            float partial = 0.f;
            #pragma unroll
            for (int i = 0; i < 16; ++i) {
                int og = ti * 32 + h * 16 + i;
                partial += fmaxf(tr[(h * 16 + i) * 33 + m] + c1b[og], 0.f) * c2w[og];
            }
            float tot = partial + __shfl_xor(partial, 32);
            if (lane < 32) dpart[ti][m] = tot;
        }
    }
    __syncthreads();
    if (t < 32)
        dynb[(size_t)b * 4096 + n0 + t] =
            c2b[0] + dpart[0][t] + dpart[1][t] + dpart[2][t] + dpart[3][t];
}

// ---------------------------------------------------------------------------
// attn_final: FUSED flash attention + merge + out-proj + sigmoid residual.
// One block = one 32-px group, 16 waves = (4 heads) x (4 key-quarters kb).
// Flash chain software-pipelined: K 4-deep, V 2-deep register rotation.
// out_w is loaded as FP32 in the out-proj section (post-chain, registers
// free) and packed inline - no convert kernel. grid 256 x 1024.
// ---------------------------------------------------------------------------
__global__ __launch_bounds__(1024, 4) void attn_final_kernel(
    const ushort* __restrict__ Qb, const ushort* __restrict__ Kb,
    const ushort* __restrict__ Vsw, const float* __restrict__ dynb,
    const float* __restrict__ out_w, const float* __restrict__ x,
    const float* __restrict__ gamma, float* __restrict__ out)
{
    __shared__ float2 OM[4][4][8][32];   // [kb][head][d/2][px]  32 KB
    __shared__ float  LM[4][4][32];      // [kb][head][px]        2 KB

    const int t    = threadIdx.x;
    const int w    = t >> 6;          // 0..15
    const int lane = t & 63;
    const int c    = lane & 31;       // px within group / A-row (gemm)
    const int h    = lane >> 5;
    const int hd   = w & 3;           // head
    const int kb   = w >> 2;          // key-quarter (0..3)
    const int pg   = blockIdx.x;
    const int b    = pg >> 7;
    const int n0   = (pg & 127) * 32;
    const int bh   = b * 4 + hd;

    // ---------------- pipelined flash chain: 32 iters over this quarter --------
    const bf16x8 qf = *(const bf16x8*)(Qb + ((size_t)bh * 4096 + n0 + c) * 16 + h * 8);

    f32x16 oacc, zf;
    #pragma unroll
    for (int i = 0; i < 16; ++i) { oacc[i] = 0.f; zf[i] = 0.f; }

    const ushort* kp = Kb + ((size_t)bh * 4096 + kb * 1024 + c) * 16 + h * 8;
    const ushort* vb = Vsw + (size_t)bh * 65536 + ((size_t)kb * 256 + h) * 64 + c * 4;

    BF8 cones;
    {
        const uint f = (c == 16) ? 0x3F803F80u : 0u;   // ones row -> l
        cones.u[0] = f; cones.u[1] = f; cones.u[2] = f; cones.u[3] = f;
    }

    // prologue: K 4-deep, V 2-deep
    bf16x8 k0 = *(const bf16x8*)kp; kp += 512;
    bf16x8 k1 = *(const bf16x8*)kp; kp += 512;
    bf16x8 k2 = *(const bf16x8*)kp; kp += 512;
    bf16x8 k3 = *(const bf16x8*)kp; kp += 512;
    uint2 vA0 = *(const uint2*)(vb),       vB0 = *(const uint2*)(vb + 128);
    uint2 vC0 = *(const uint2*)(vb + 256), vD0 = *(const uint2*)(vb + 384);
    vb += 512;
    uint2 vA1 = *(const uint2*)(vb),       vB1 = *(const uint2*)(vb + 128);
    uint2 vC1 = *(const uint2*)(vb + 256), vD1 = *(const uint2*)(vb + 384);
    vb += 512;

#define STEP(K, VA, VB, VC, VD)                                                      \
    {                                                                                \
        __builtin_amdgcn_s_setprio(1);                                               \
        f32x16 s = __builtin_amdgcn_mfma_f32_32x32x16_bf16(K, qf, zf, 0, 0, 0);      \
        __builtin_amdgcn_s_setprio(0);                                               \
        K = *(const bf16x8*)kp; kp += 512;                                           \
        BF8 p1, p2;                                                                  \
        p1.u[0] = cvt_pk_bf(__builtin_amdgcn_exp2f(s[0]),  __builtin_amdgcn_exp2f(s[1]));  \
        p1.u[1] = cvt_pk_bf(__builtin_amdgcn_exp2f(s[2]),  __builtin_amdgcn_exp2f(s[3]));  \
        p1.u[2] = cvt_pk_bf(__builtin_amdgcn_exp2f(s[4]),  __builtin_amdgcn_exp2f(s[5]));  \
        p1.u[3] = cvt_pk_bf(__builtin_amdgcn_exp2f(s[6]),  __builtin_amdgcn_exp2f(s[7]));  \
        p2.u[0] = cvt_pk_bf(__builtin_amdgcn_exp2f(s[8]),  __builtin_amdgcn_exp2f(s[9]));  \
        p2.u[1] = cvt_pk_bf(__builtin_amdgcn_exp2f(s[10]), __builtin_amdgcn_exp2f(s[11])); \
        p2.u[2] = cvt_pk_bf(__builtin_amdgcn_exp2f(s[12]), __builtin_amdgcn_exp2f(s[13])); \
        p2.u[3] = cvt_pk_bf(__builtin_amdgcn_exp2f(s[14]), __builtin_amdgcn_exp2f(s[15])); \
        BF8 a1, a2;                                                                  \
        if (c < 16) {                                                                \
            a1.u[0] = VA.x; a1.u[1] = VA.y; a1.u[2] = VB.x; a1.u[3] = VB.y;          \
            a2.u[0] = VC.x; a2.u[1] = VC.y; a2.u[2] = VD.x; a2.u[3] = VD.y;          \
        } else { a1 = cones; a2 = cones; }                                           \
        VA = *(const uint2*)(vb);       VB = *(const uint2*)(vb + 128);              \
        VC = *(const uint2*)(vb + 256); VD = *(const uint2*)(vb + 384);              \
        vb += 512;                                                                   \
        __builtin_amdgcn_s_setprio(1);                                               \
        oacc = __builtin_amdgcn_mfma_f32_32x32x16_bf16(a1.v, p1.v, oacc, 0, 0, 0);   \
        oacc = __builtin_amdgcn_mfma_f32_32x32x16_bf16(a2.v, p2.v, oacc, 0, 0, 0);   \
        __builtin_amdgcn_s_setprio(0);                                               \
    }

    for (int it = 0; it < 8; ++it) {
        STEP(k0, vA0, vB0, vC0, vD0);
        STEP(k1, vA1, vB1, vC1, vD1);
        STEP(k2, vA0, vB0, vC0, vD0);
        STEP(k3, vA1, vB1, vC1, vD1);
    }
#undef STEP

    // ---------------- merge into LDS ----------------
    OM[kb][hd][2 * h + 0][c] = make_float2(oacc[0], oacc[1]);
    OM[kb][hd][2 * h + 1][c] = make_float2(oacc[2], oacc[3]);
    OM[kb][hd][4 + 2 * h][c] = make_float2(oacc[4], oacc[5]);
    OM[kb][hd][5 + 2 * h][c] = make_float2(oacc[6], oacc[7]);
    if (h == 0) LM[kb][hd][c] = oacc[8];
    __syncthreads();

    // ---------------- out-proj GEMM: waves 0-7 -> channels w*32..w*32+31 --------
    if (w < 8) {
        const int m = c;                              // px col = A row index
        const float dyn_px = dynb[(size_t)b * 4096 + n0 + m];

        // issue all out_w fp32 loads up front (post-chain: registers are free)
        const float* ap = out_w + (size_t)(w * 32 + m) * 64 + h * 8;
        float4 a00 = *(const float4*)(ap +  0); float4 a01 = *(const float4*)(ap +  4);
        float4 a10 = *(const float4*)(ap + 16); float4 a11 = *(const float4*)(ap + 20);
        float4 a20 = *(const float4*)(ap + 32); float4 a21 = *(const float4*)(ap + 36);
        float4 a30 = *(const float4*)(ap + 48); float4 a31 = *(const float4*)(ap + 52);
        bf16x8 af[4];
        {
            BF8 t0, t1, t2, t3;
            t0.u[0] = pack_bf(a00.x, a00.y); t0.u[1] = pack_bf(a00.z, a00.w);
            t0.u[2] = pack_bf(a01.x, a01.y); t0.u[3] = pack_bf(a01.z, a01.w);
            t1.u[0] = pack_bf(a10.x, a10.y); t1.u[1] = pack_bf(a10.z, a10.w);
            t1.u[2] = pack_bf(a11.x, a11.y); t1.u[3] = pack_bf(a11.z, a11.w);
            t2.u[0] = pack_bf(a20.x, a20.y); t2.u[1] = pack_bf(a20.z, a20.w);
            t2.u[2] = pack_bf(a21.x, a21.y); t2.u[3] = pack_bf(a21.z, a21.w);
            t3.u[0] = pack_bf(a30.x, a30.y); t3.u[1] = pack_bf(a30.z, a30.w);
            t3.u[2] = pack_bf(a31.x, a31.y); t3.u[3] = pack_bf(a31.z, a31.w);
            af[0] = t0.v; af[1] = t1.v; af[2] = t2.v; af[3] = t3.v;
        }

        f32x16 acc;
        #pragma unroll
        for (int i = 0; i < 16; ++i) acc[i] = 0.f;

        #pragma unroll
        for (int ks = 0; ks < 4; ++ks) {              // kstep = head
            float l = LM[0][ks][m] + LM[1][ks][m] + LM[2][ks][m] + LM[3][ks][m];
            float fac = dyn_px / l;
            BF8 bfr;
            #pragma unroll
            for (int i = 0; i < 4; ++i) {
                int sl = 4 * h + i;                   // d-pair slot
                float2 s0 = OM[0][ks][sl][m];
                float2 s1 = OM[1][ks][sl][m];
                float2 s2 = OM[2][ks][sl][m];
                float2 s3 = OM[3][ks][sl][m];
                float e0 = (s0.x + s1.x + s2.x + s3.x) * fac;
                float e1 = (s0.y + s1.y + s2.y + s3.y) * fac;
                bfr.u[i] = pack_bf(e0, e1);
            }
            acc = __builtin_amdgcn_mfma_f32_32x32x16_bf16(af[ks], bfr.v, acc, 0, 0, 0);
        }

        // ------- epilogue: direct store (2x128B segments per r, coalesced) ------
        const float g = gamma[0];
        #pragma unroll
        for (int r = 0; r < 16; ++r) {
            int o = (r & 3) + 8 * (r >> 2) + 4 * h;   // out channel within tile
            size_t idx = ((size_t)b * 256 + w * 32 + o) * 4096 + n0 + m;
            float z = g * acc[r] + x[idx];
            out[idx] = 1.f / (1.f + __builtin_amdgcn_exp2f(-z * LOG2E));
        }
    }
}

// ---------------------------------------------------------------------------
extern "C" void kernel_launch(void* const* d_in, const int* in_sizes, int n_in,
                              void* d_out, int out_size, void* d_ws, size_t ws_size,
                              hipStream_t stream)
{
    const float* x      = (const float*)d_in[0];
    const float* norm_w = (const float*)d_in[1];
    const float* norm_b = (const float*)d_in[2];
    const float* qkv_w  = (const float*)d_in[3];
    const float* out_w  = (const float*)d_in[4];
    const float* c1w    = (const float*)d_in[5];
    const float* c1b    = (const float*)d_in[6];
    const float* c2w    = (const float*)d_in[7];
    const float* c2b    = (const float*)d_in[8];
    const float* gamma  = (const float*)d_in[9];

    char* ws = (char*)d_ws;
    ushort* Qb   = (ushort*)ws;                 // 524288 ush (1 MB)
    ushort* Kb   = Qb + 524288;                 // 1 MB
    ushort* Vsw  = Kb + 524288;                 // 1 MB
    float*  dynb = (float*)(ws + 3145728);      // 8192 floats

    hipLaunchKernelGGL(lnqkv_kernel, dim3(256), dim3(1024), 0, stream,
                       x, norm_w, norm_b, qkv_w, c1w, c1b, c2w, c2b,
                       Qb, Kb, Vsw, dynb);
    hipLaunchKernelGGL(attn_final_kernel, dim3(256), dim3(1024), 0, stream,
                       Qb, Kb, Vsw, dynb, out_w, x, gamma, (float*)d_out);
}

// Round 11
// 111.378 us; speedup vs baseline: 1.0473x; 1.0473x over previous
//
#include <hip/hip_runtime.h>
#include <cstdint>
#include <cstddef>

#define LOG2E 1.44269504088896340736f

typedef float  f32x16 __attribute__((ext_vector_type(16)));
typedef __bf16 bf16x8 __attribute__((ext_vector_type(8)));

union BF8 { bf16x8 v; uint u[4]; ushort us[8]; };

// pack two floats to bf16 pair (round-half-up), a -> lo16, b -> hi16
__device__ __forceinline__ uint pack_bf(float a, float b) {
    uint ua = __float_as_uint(a) + 0x8000u;
    uint ub = __float_as_uint(b) + 0x8000u;
    return __builtin_amdgcn_perm(ub, ua, 0x07060302u);
}
// pack two floats to bf16 pair via HW cvt (RNE), a -> lo16, b -> hi16
__device__ __forceinline__ uint cvt_pk_bf(float a, float b) {
    uint r;
    asm("v_cvt_pk_bf16_f32 %0, %1, %2" : "=v"(r) : "v"(a), "v"(b));
    return r;
}

// ---------------------------------------------------------------------------
// convert_w: fp32 -> bf16 weights. qkv_w rows o<64 (=Q) pre-scaled 0.25*log2e.
// concat layout: qkv_w[49152] | c1w[32768] | out_w[16384] = 98304 elems.
// grid 96 x 256, one float4 per thread.
// ---------------------------------------------------------------------------
__global__ __launch_bounds__(256) void convert_w_kernel(
    const float* __restrict__ qkv_w, const float* __restrict__ c1w,
    const float* __restrict__ out_w,
    ushort* __restrict__ qkvw_b, ushort* __restrict__ c1w_b, ushort* __restrict__ ow_b)
{
    const int g = (blockIdx.x * 256 + threadIdx.x) * 4;
    const float* src; ushort* dst; int off; float sc = 1.f;
    if (g < 49152)      { src = qkv_w; dst = qkvw_b; off = g;
                          if (g < 16384) sc = 0.25f * LOG2E; }
    else if (g < 81920) { src = c1w;   dst = c1w_b;  off = g - 49152; }
    else                { src = out_w; dst = ow_b;   off = g - 81920; }
    float4 v = *(const float4*)(src + off);
    uint2 pk;
    pk.x = pack_bf(v.x * sc, v.y * sc);
    pk.y = pack_bf(v.z * sc, v.w * sc);
    *(uint2*)(dst + off) = pk;
}

// ---------------------------------------------------------------------------
// lnqkv: FUSED LayerNorm + QKV/conv MFMA GEMMs. One block = one 32-px group,
// 1024 threads / 16 waves. All 16 bf16 A-weight fragments per wave are
// preloaded into registers AT KERNEL ENTRY (T14) - their L2 latency hides
// under the LN phase; the GEMM chain then runs with zero VMEM stalls (LDS
// B-reads only, fully unrolled so afr[] is static-indexed -> no scratch).
// grid 256 x 1024.
// ---------------------------------------------------------------------------
__global__ __launch_bounds__(1024) void lnqkv_kernel(
    const float* __restrict__ x, const float* __restrict__ nw, const float* __restrict__ nb,
    const ushort* __restrict__ qkvw_b, const ushort* __restrict__ c1w_b,
    const float* __restrict__ c1b, const float* __restrict__ c2w,
    const float* __restrict__ c2b,
    ushort* __restrict__ Qb, ushort* __restrict__ Kb, ushort* __restrict__ Vsw,
    float* __restrict__ dynb)
{
    __shared__ union {
        struct {
            uint  XN[32 * 32 * 4];   // [u][px][4 uint=8 bf16] 16 KB
            uint  XR[32 * 32 * 4];   // raw x, same layout     16 KB
            float red1[1024];        //                         4 KB
            float red2[1024];        //                         4 KB
        } p;
        float trans[10][33 * 32];    // epilogue, aliases above (42.2 KB)
    } S;
    __shared__ float muS[32], rsS[32];
    __shared__ float dpart[4][32];

    const int t    = threadIdx.x;
    const int pg   = blockIdx.x;
    const int b    = pg >> 7;
    const int n0   = (pg & 127) * 32;
    const int w    = t >> 6;          // 0..15
    const int lane = t & 63;
    const int m    = lane & 31;       // A-row / C-col index (= px for B)
    const int h    = lane >> 5;       // k-slot half

    // -------- A-fragment preload (issued NOW; latency hides under LN) --------
    bf16x8 afr[16];
    if (w < 6) {
        const int qkv = w >> 1;       // 0=Q 1=K 2=V
        const int ti  = w & 1;
        const ushort* ap = qkvw_b + (size_t)(qkv * 64 + ti * 32 + m) * 256 + h * 8;
        #pragma unroll
        for (int ks = 0; ks < 16; ++ks) afr[ks] = *(const bf16x8*)(ap + ks * 16);
    } else if (w < 10) {
        const ushort* ap = c1w_b + (size_t)((w - 6) * 32 + m) * 256 + h * 8;
        #pragma unroll
        for (int ks = 0; ks < 16; ++ks) afr[ks] = *(const bf16x8*)(ap + ks * 16);
    }

    // ------------------ Phase 1: LayerNorm into LDS ------------------
    {
        const int j  = t & 31;            // px
        const int cg = t >> 5;            // channel group (8 ch each), 0..31
        const size_t xb = (size_t)b * 256 * 4096 + n0 + j;
        float v[8];
        #pragma unroll
        for (int i = 0; i < 8; ++i) v[i] = x[xb + (size_t)(cg * 8 + i) * 4096];
        float s1 = 0.f, s2 = 0.f;
        #pragma unroll
        for (int i = 0; i < 8; ++i) { s1 += v[i]; s2 += v[i] * v[i]; }
        uint4 pk;
        pk.x = pack_bf(v[0], v[1]); pk.y = pack_bf(v[2], v[3]);
        pk.z = pack_bf(v[4], v[5]); pk.w = pack_bf(v[6], v[7]);
        *(uint4*)&S.p.XR[(cg * 32 + j) * 4] = pk;
        S.p.red1[t] = s1; S.p.red2[t] = s2;
        __syncthreads();
        if (t < 32) {
            float a = 0.f, q = 0.f;
            #pragma unroll 8
            for (int g2 = 0; g2 < 32; ++g2) { a += S.p.red1[g2 * 32 + t]; q += S.p.red2[g2 * 32 + t]; }
            float mu  = a * (1.f / 256.f);
            float var = q * (1.f / 256.f) - mu * mu;
            muS[t] = mu; rsS[t] = rsqrtf(fmaxf(var, 0.f) + 1e-5f);
        }
        __syncthreads();
        const float mu = muS[j], rs = rsS[j];
        const float4 w0 = *(const float4*)(nw + cg * 8);
        const float4 w1 = *(const float4*)(nw + cg * 8 + 4);
        const float4 b0 = *(const float4*)(nb + cg * 8);
        const float4 b1 = *(const float4*)(nb + cg * 8 + 4);
        float e0 = (v[0] - mu) * rs * w0.x + b0.x;
        float e1 = (v[1] - mu) * rs * w0.y + b0.y;
        float e2 = (v[2] - mu) * rs * w0.z + b0.z;
        float e3 = (v[3] - mu) * rs * w0.w + b0.w;
        float e4 = (v[4] - mu) * rs * w1.x + b1.x;
        float e5 = (v[5] - mu) * rs * w1.y + b1.y;
        float e6 = (v[6] - mu) * rs * w1.z + b1.z;
        float e7 = (v[7] - mu) * rs * w1.w + b1.w;
        uint4 o;
        o.x = pack_bf(e0, e1); o.y = pack_bf(e2, e3);
        o.z = pack_bf(e4, e5); o.w = pack_bf(e6, e7);
        *(uint4*)&S.p.XN[(cg * 32 + j) * 4] = o;
    }
    __syncthreads();

    // ------------------ Phase 2: MFMA GEMMs from LDS + reg A ------------------
    const ushort* xnB = (const ushort*)S.p.XN;
    const ushort* xrB = (const ushort*)S.p.XR;

    f32x16 acc;
    #pragma unroll
    for (int i = 0; i < 16; ++i) acc[i] = 0.f;

    if (w < 6) {
        #pragma unroll
        for (int ks = 0; ks < 16; ++ks) {
            bf16x8 bf = *(const bf16x8*)(xnB + ((ks * 2 + h) * 32 + m) * 8);
            acc = __builtin_amdgcn_mfma_f32_32x32x16_bf16(afr[ks], bf, acc, 0, 0, 0);
        }
    } else if (w < 10) {
        #pragma unroll
        for (int ks = 0; ks < 16; ++ks) {
            bf16x8 bf = *(const bf16x8*)(xrB + ((ks * 2 + h) * 32 + m) * 8);
            acc = __builtin_amdgcn_mfma_f32_32x32x16_bf16(afr[ks], bf, acc, 0, 0, 0);
        }
    }
    __syncthreads();   // all XN/XR reads done; trans (aliased) now writable

    if (w < 10) {
        float* tr = S.trans[w];
        #pragma unroll
        for (int r = 0; r < 16; ++r)
            tr[((r & 3) + 8 * (r >> 2) + 4 * h) * 33 + m] = acc[r];

        if (w < 4) {                       // Q/K tiles
            const int qkv = w >> 1, ti = w & 1;
            ushort* dst = (qkv == 0) ? Qb : Kb;
            #pragma unroll
            for (int it = 0; it < 2; ++it) {
                int unit = it * 2 + h;            // 0..3
                int hl = unit >> 1, half = unit & 1;
                float v0 = tr[(hl * 16 + half * 8 + 0) * 33 + m];
                float v1 = tr[(hl * 16 + half * 8 + 1) * 33 + m];
                float v2 = tr[(hl * 16 + half * 8 + 2) * 33 + m];
                float v3 = tr[(hl * 16 + half * 8 + 3) * 33 + m];
                float v4 = tr[(hl * 16 + half * 8 + 4) * 33 + m];
                float v5 = tr[(hl * 16 + half * 8 + 5) * 33 + m];
                float v6 = tr[(hl * 16 + half * 8 + 6) * 33 + m];
                float v7 = tr[(hl * 16 + half * 8 + 7) * 33 + m];
                uint4 pk;
                pk.x = pack_bf(v0, v1); pk.y = pack_bf(v2, v3);
                pk.z = pack_bf(v4, v5); pk.w = pack_bf(v6, v7);
                int head = ti * 2 + hl;
                *(uint4*)(dst + ((size_t)(b * 4 + head) * 4096 + n0 + m) * 16 + half * 8) = pk;
            }
        } else if (w < 6) {                // V tile
            const int ti = w & 1;
            int d = lane & 15, u = lane >> 4;
            #pragma unroll
            for (int it = 0; it < 4; ++it) {
                int unit = it * 4 + u;            // 0..15
                int hl = unit >> 3, sg = unit & 7;
                float v0 = tr[(hl * 16 + d) * 33 + sg * 4 + 0];
                float v1 = tr[(hl * 16 + d) * 33 + sg * 4 + 1];
                float v2 = tr[(hl * 16 + d) * 33 + sg * 4 + 2];
                float v3 = tr[(hl * 16 + d) * 33 + sg * 4 + 3];
                uint2 pk; pk.x = pack_bf(v0, v1); pk.y = pack_bf(v2, v3);
                int head = ti * 2 + hl;
                *(uint2*)(Vsw + (((size_t)(b * 4 + head) * 1024 + (pg & 127) * 8 + sg) * 16 + d) * 4) = pk;
            }
        } else {                           // conv tile ti = w-6
            const int ti = w - 6;
            float partial = 0.f;
            #pragma unroll
            for (int i = 0; i < 16; ++i) {
                int og = ti * 32 + h * 16 + i;
                partial += fmaxf(tr[(h * 16 + i) * 33 + m] + c1b[og], 0.f) * c2w[og];
            }
            float tot = partial + __shfl_xor(partial, 32);
            if (lane < 32) dpart[ti][m] = tot;
        }
    }
    __syncthreads();
    if (t < 32)
        dynb[(size_t)b * 4096 + n0 + t] =
            c2b[0] + dpart[0][t] + dpart[1][t] + dpart[2][t] + dpart[3][t];
}

// ---------------------------------------------------------------------------
// attn_final: FUSED flash attention + merge + out-proj + sigmoid residual.
// One block = one 32-px group, 16 waves = (4 heads) x (4 key-quarters kb).
// Flash chain software-pipelined: K 4-deep, V 2-deep register rotation.
// P-packing via v_cvt_pk_bf16_f32. A = out_w bf16 (pre-converted).
// grid 256 x 1024.
// ---------------------------------------------------------------------------
__global__ __launch_bounds__(1024, 4) void attn_final_kernel(
    const ushort* __restrict__ Qb, const ushort* __restrict__ Kb,
    const ushort* __restrict__ Vsw, const float* __restrict__ dynb,
    const ushort* __restrict__ ow_b, const float* __restrict__ x,
    const float* __restrict__ gamma, float* __restrict__ out)
{
    __shared__ float2 OM[4][4][8][32];   // [kb][head][d/2][px]  32 KB
    __shared__ float  LM[4][4][32];      // [kb][head][px]        2 KB

    const int t    = threadIdx.x;
    const int w    = t >> 6;          // 0..15
    const int lane = t & 63;
    const int c    = lane & 31;       // px within group / A-row (gemm)
    const int h    = lane >> 5;
    const int hd   = w & 3;           // head
    const int kb   = w >> 2;          // key-quarter (0..3)
    const int pg   = blockIdx.x;
    const int b    = pg >> 7;
    const int n0   = (pg & 127) * 32;
    const int bh   = b * 4 + hd;

    // ---------------- pipelined flash chain: 32 iters over this quarter --------
    const bf16x8 qf = *(const bf16x8*)(Qb + ((size_t)bh * 4096 + n0 + c) * 16 + h * 8);

    f32x16 oacc, zf;
    #pragma unroll
    for (int i = 0; i < 16; ++i) { oacc[i] = 0.f; zf[i] = 0.f; }

    const ushort* kp = Kb + ((size_t)bh * 4096 + kb * 1024 + c) * 16 + h * 8;
    const ushort* vb = Vsw + (size_t)bh * 65536 + ((size_t)kb * 256 + h) * 64 + c * 4;

    BF8 cones;
    {
        const uint f = (c == 16) ? 0x3F803F80u : 0u;   // ones row -> l
        cones.u[0] = f; cones.u[1] = f; cones.u[2] = f; cones.u[3] = f;
    }

    // prologue: K 4-deep, V 2-deep
    bf16x8 k0 = *(const bf16x8*)kp; kp += 512;
    bf16x8 k1 = *(const bf16x8*)kp; kp += 512;
    bf16x8 k2 = *(const bf16x8*)kp; kp += 512;
    bf16x8 k3 = *(const bf16x8*)kp; kp += 512;
    uint2 vA0 = *(const uint2*)(vb),       vB0 = *(const uint2*)(vb + 128);
    uint2 vC0 = *(const uint2*)(vb + 256), vD0 = *(const uint2*)(vb + 384);
    vb += 512;
    uint2 vA1 = *(const uint2*)(vb),       vB1 = *(const uint2*)(vb + 128);
    uint2 vC1 = *(const uint2*)(vb + 256), vD1 = *(const uint2*)(vb + 384);
    vb += 512;

#define STEP(K, VA, VB, VC, VD)                                                      \
    {                                                                                \
        __builtin_amdgcn_s_setprio(1);                                               \
        f32x16 s = __builtin_amdgcn_mfma_f32_32x32x16_bf16(K, qf, zf, 0, 0, 0);      \
        __builtin_amdgcn_s_setprio(0);                                               \
        K = *(const bf16x8*)kp; kp += 512;                                           \
        BF8 p1, p2;                                                                  \
        p1.u[0] = cvt_pk_bf(__builtin_amdgcn_exp2f(s[0]),  __builtin_amdgcn_exp2f(s[1]));  \
        p1.u[1] = cvt_pk_bf(__builtin_amdgcn_exp2f(s[2]),  __builtin_amdgcn_exp2f(s[3]));  \
        p1.u[2] = cvt_pk_bf(__builtin_amdgcn_exp2f(s[4]),  __builtin_amdgcn_exp2f(s[5]));  \
        p1.u[3] = cvt_pk_bf(__builtin_amdgcn_exp2f(s[6]),  __builtin_amdgcn_exp2f(s[7]));  \
        p2.u[0] = cvt_pk_bf(__builtin_amdgcn_exp2f(s[8]),  __builtin_amdgcn_exp2f(s[9]));  \
        p2.u[1] = cvt_pk_bf(__builtin_amdgcn_exp2f(s[10]), __builtin_amdgcn_exp2f(s[11])); \
        p2.u[2] = cvt_pk_bf(__builtin_amdgcn_exp2f(s[12]), __builtin_amdgcn_exp2f(s[13])); \
        p2.u[3] = cvt_pk_bf(__builtin_amdgcn_exp2f(s[14]), __builtin_amdgcn_exp2f(s[15])); \
        BF8 a1, a2;                                                                  \
        if (c < 16) {                                                                \
            a1.u[0] = VA.x; a1.u[1] = VA.y; a1.u[2] = VB.x; a1.u[3] = VB.y;          \
            a2.u[0] = VC.x; a2.u[1] = VC.y; a2.u[2] = VD.x; a2.u[3] = VD.y;          \
        } else { a1 = cones; a2 = cones; }                                           \
        VA = *(const uint2*)(vb);       VB = *(const uint2*)(vb + 128);              \
        VC = *(const uint2*)(vb + 256); VD = *(const uint2*)(vb + 384);              \
        vb += 512;                                                                   \
        __builtin_amdgcn_s_setprio(1);                                               \
        oacc = __builtin_amdgcn_mfma_f32_32x32x16_bf16(a1.v, p1.v, oacc, 0, 0, 0);   \
        oacc = __builtin_amdgcn_mfma_f32_32x32x16_bf16(a2.v, p2.v, oacc, 0, 0, 0);   \
        __builtin_amdgcn_s_setprio(0);                                               \
    }

    for (int it = 0; it < 8; ++it) {
        STEP(k0, vA0, vB0, vC0, vD0);
        STEP(k1, vA1, vB1, vC1, vD1);
        STEP(k2, vA0, vB0, vC0, vD0);
        STEP(k3, vA1, vB1, vC1, vD1);
    }
#undef STEP

    // ---------------- merge into LDS ----------------
    OM[kb][hd][2 * h + 0][c] = make_float2(oacc[0], oacc[1]);
    OM[kb][hd][2 * h + 1][c] = make_float2(oacc[2], oacc[3]);
    OM[kb][hd][4 + 2 * h][c] = make_float2(oacc[4], oacc[5]);
    OM[kb][hd][5 + 2 * h][c] = make_float2(oacc[6], oacc[7]);
    if (h == 0) LM[kb][hd][c] = oacc[8];
    __syncthreads();

    // ---------------- out-proj GEMM: waves 0-7 -> channels w*32..w*32+31 --------
    if (w < 8) {
        const int m = c;                              // px col = A row index
        const float dyn_px = dynb[(size_t)b * 4096 + n0 + m];

        f32x16 acc;
        #pragma unroll
        for (int i = 0; i < 16; ++i) acc[i] = 0.f;

        #pragma unroll
        for (int ks = 0; ks < 4; ++ks) {              // kstep = head
            float l = LM[0][ks][m] + LM[1][ks][m] + LM[2][ks][m] + LM[3][ks][m];
            float fac = dyn_px / l;
            BF8 bfr;
            #pragma unroll
            for (int i = 0; i < 4; ++i) {
                int sl = 4 * h + i;                   // d-pair slot
                float2 s0 = OM[0][ks][sl][m];
                float2 s1 = OM[1][ks][sl][m];
                float2 s2 = OM[2][ks][sl][m];
                float2 s3 = OM[3][ks][sl][m];
                float e0 = (s0.x + s1.x + s2.x + s3.x) * fac;
                float e1 = (s0.y + s1.y + s2.y + s3.y) * fac;
                bfr.u[i] = pack_bf(e0, e1);
            }
            bf16x8 af = *(const bf16x8*)(ow_b + (size_t)(w * 32 + m) * 64 + ks * 16 + h * 8);
            acc = __builtin_amdgcn_mfma_f32_32x32x16_bf16(af, bfr.v, acc, 0, 0, 0);
        }

        // ------- epilogue: direct store (2x128B segments per r, coalesced) ------
        const float g = gamma[0];
        #pragma unroll
        for (int r = 0; r < 16; ++r) {
            int o = (r & 3) + 8 * (r >> 2) + 4 * h;   // out channel within tile
            size_t idx = ((size_t)b * 256 + w * 32 + o) * 4096 + n0 + m;
            float z = g * acc[r] + x[idx];
            out[idx] = 1.f / (1.f + __builtin_amdgcn_exp2f(-z * LOG2E));
        }
    }
}

// ---------------------------------------------------------------------------
extern "C" void kernel_launch(void* const* d_in, const int* in_sizes, int n_in,
                              void* d_out, int out_size, void* d_ws, size_t ws_size,
                              hipStream_t stream)
{
    const float* x      = (const float*)d_in[0];
    const float* norm_w = (const float*)d_in[1];
    const float* norm_b = (const float*)d_in[2];
    const float* qkv_w  = (const float*)d_in[3];
    const float* out_w  = (const float*)d_in[4];
    const float* c1w    = (const float*)d_in[5];
    const float* c1b    = (const float*)d_in[6];
    const float* c2w    = (const float*)d_in[7];
    const float* c2b    = (const float*)d_in[8];
    const float* gamma  = (const float*)d_in[9];

    char* ws = (char*)d_ws;
    ushort* Qb     = (ushort*)ws;                 // 524288 ush (1 MB)
    ushort* Kb     = Qb + 524288;                 // 1 MB
    ushort* Vsw    = Kb + 524288;                 // 1 MB
    ushort* qkvw_b = Vsw + 524288;                // 49152 ush
    ushort* c1w_b  = qkvw_b + 49152;              // 32768 ush
    ushort* ow_b   = c1w_b + 32768;               // 16384 ush
    float*  dynb   = (float*)(ws + 3342336);      // 8192 floats

    hipLaunchKernelGGL(convert_w_kernel, dim3(96), dim3(256), 0, stream,
                       qkv_w, c1w, out_w, qkvw_b, c1w_b, ow_b);
    hipLaunchKernelGGL(lnqkv_kernel, dim3(256), dim3(1024), 0, stream,
                       x, norm_w, norm_b, qkvw_b, c1w_b, c1b, c2w, c2b,
                       Qb, Kb, Vsw, dynb);
    hipLaunchKernelGGL(attn_final_kernel, dim3(256), dim3(1024), 0, stream,
                       Qb, Kb, Vsw, dynb, ow_b, x, gamma, (float*)d_out);
}